// Round 3
// baseline (267.539 us; speedup 1.0000x reference)
//
#include <hip/hip_runtime.h>
#include <hip/hip_bf16.h>

// B=2, T=2048, C=1024, H=16, Dh=64
// ws layout (bytes), total 44,040,192:
//   xb   [4096x1024] bf16 @ 0          -- reused as vt [2][16][64][2048] after qkv GEMM
//   wat  [3072x1024] bf16 @ 8388608    -- reused as yb [4096x1024] bf16 after qkv GEMM
//   qkv  [4096x3072] bf16 @ 16777216
//   wpt  [1024x1024] bf16 @ 41943040

typedef __attribute__((ext_vector_type(8))) __bf16 bf16x8;
typedef __attribute__((ext_vector_type(4))) float  floatx4;
typedef __attribute__((ext_vector_type(4))) float  fvec4;
typedef __attribute__((ext_vector_type(4))) short  short4v;

#define MFMA16(a, b, c) __builtin_amdgcn_mfma_f32_16x16x32_bf16(a, b, c, 0, 0, 0)

using as1v = const __attribute__((address_space(1))) void;
using as3v = __attribute__((address_space(3))) void;
__device__ __forceinline__ void async16(const void* g, void* l) {
  __builtin_amdgcn_global_load_lds((as1v*)g, (as3v*)l, 16, 0, 0);
}

__device__ inline void store_out(float* p, float v) { *p = v; }
__device__ inline void store_out(__hip_bfloat16* p, float v) { *p = __float2bfloat16(v); }

// ---------------- cast fp32 -> bf16 ----------------
__global__ __launch_bounds__(256) void cast_bf16_kernel(const float* __restrict__ in,
                                                        __hip_bfloat16* __restrict__ out,
                                                        int n) {
  int i = (blockIdx.x * 256 + threadIdx.x) * 4;
  if (i >= n) return;
  fvec4 v = *(const fvec4*)(in + i);
  union { short4v s; __hip_bfloat16 h[4]; } u;
#pragma unroll
  for (int j = 0; j < 4; ++j) u.h[j] = __float2bfloat16(v[j]);
  *(short4v*)((short*)out + i) = u.s;
}

// ------------- transpose + cast: in[rows][cols] f32 -> out[cols][rows] bf16 -------------
__global__ __launch_bounds__(256) void transpose_cast_kernel(const float* __restrict__ in,
                                                             __hip_bfloat16* __restrict__ out,
                                                             int rows, int cols) {
  __shared__ float tile[32][33];
  const int tx = threadIdx.x, ty = threadIdx.y;
  const int c0 = blockIdx.x * 32, r0 = blockIdx.y * 32;
#pragma unroll
  for (int i = 0; i < 32; i += 8)
    tile[ty + i][tx] = in[(long)(r0 + ty + i) * cols + c0 + tx];
  __syncthreads();
#pragma unroll
  for (int i = 0; i < 32; i += 8)
    out[(long)(c0 + ty + i) * rows + r0 + tx] = __float2bfloat16(tile[tx][ty + i]);
}

// ------------- V^T extraction: vt[b][h][d][t] = qkv[b*T+t][2048+h*64+d] -------------
__global__ __launch_bounds__(256) void vt_kernel(const __hip_bfloat16* __restrict__ qkv,
                                                 __hip_bfloat16* __restrict__ vt) {
  __shared__ __align__(16) __hip_bfloat16 tile[64 * 64];
  const int tid = threadIdx.x;
  const int tt0 = blockIdx.x * 64, h = blockIdx.y, b = blockIdx.z;
  const long bh = (long)b * 16 + h;
#pragma unroll
  for (int it = 0; it < 2; ++it) {
    const int c = it * 256 + tid;
    const int row = c >> 3, cg = c & 7;
    const int pg = cg ^ ((row >> 3) & 7);
    *(bf16x8*)(tile + row * 64 + pg * 8) =
        *(const bf16x8*)(qkv + ((long)b * 2048 + tt0 + row) * 3072 + 2048 + h * 64 + cg * 8);
  }
  __syncthreads();
#pragma unroll
  for (int it = 0; it < 2; ++it) {
    const int c = it * 256 + tid;
    const int dr = c >> 3, tg = c & 7;
    union { bf16x8 v; __hip_bfloat16 e[8]; } u;
    const int pg = (dr >> 3) ^ tg;
#pragma unroll
    for (int j = 0; j < 8; ++j)
      u.e[j] = tile[(tg * 8 + j) * 64 + pg * 8 + (dr & 7)];
    *(bf16x8*)(vt + (bh * 64 + dr) * 2048 + tt0 + tg * 8) = u.v;
  }
}

// ------------- GEMM: C[M,N] = A[M,K] * Bt[N,K]^T, m97-style global_load_lds -------------
// 128x128 tile, BK=32, 256 threads. LDS unpadded 128x32 with 16B-chunk XOR swizzle:
// phys_cg = cg ^ ((row>>1)&3) -> frag ds_read_b128 lands 2-way per bank (free, m136).
template <typename OutT>
__global__ __launch_bounds__(256) void gemm_bt_kernel(const __hip_bfloat16* __restrict__ A,
                                                      const __hip_bfloat16* __restrict__ Bt,
                                                      OutT* __restrict__ C,
                                                      int M, int N, int K) {
  __shared__ __align__(16) __hip_bfloat16 As[128 * 32];
  __shared__ __align__(16) __hip_bfloat16 Bs[128 * 32];
  const int tid = threadIdx.x;
  const int lane = tid & 63, wv = tid >> 6;
  const int l15 = lane & 15, quad = lane >> 4;
  const int wm = wv >> 1, wn = wv & 1;
  const long m0 = (long)blockIdx.y * 128, n0 = (long)blockIdx.x * 128;
  floatx4 acc[4][4] = {};
  const int nk = K >> 5;
  // this thread's staging chunk (per it): lds chunk c = it*256+tid, row=c>>2, phys cg=c&3
  for (int kt = 0; kt < nk; ++kt) {
    const int k0 = kt << 5;
    __syncthreads();  // previous tile's readers done
#pragma unroll
    for (int it = 0; it < 2; ++it) {
      const int c = it * 256 + tid;
      const int row = c >> 2;
      const int lcg = (c & 3) ^ ((row >> 1) & 3);
      const int ldsoff = (it * 256 + wv * 64) * 16;  // wave-uniform base (bytes)
      async16(A + (m0 + row) * K + k0 + lcg * 8, (char*)As + ldsoff);
      async16(Bt + (n0 + row) * K + k0 + lcg * 8, (char*)Bs + ldsoff);
    }
    __syncthreads();  // drains vmcnt -> LDS ready
    bf16x8 af[4], bfr[4];
#pragma unroll
    for (int t = 0; t < 4; ++t) {
      const int ar = wm * 64 + t * 16 + l15;
      const int br = wn * 64 + t * 16 + l15;
      af[t]  = *(const bf16x8*)(As + ar * 32 + (quad ^ ((ar >> 1) & 3)) * 8);
      bfr[t] = *(const bf16x8*)(Bs + br * 32 + (quad ^ ((br >> 1) & 3)) * 8);
    }
#pragma unroll
    for (int mt = 0; mt < 4; ++mt)
#pragma unroll
      for (int nt = 0; nt < 4; ++nt)
        acc[mt][nt] = MFMA16(af[mt], bfr[nt], acc[mt][nt]);
  }
#pragma unroll
  for (int mt = 0; mt < 4; ++mt)
#pragma unroll
    for (int nt = 0; nt < 4; ++nt)
#pragma unroll
      for (int r = 0; r < 4; ++r) {
        const long row = m0 + wm * 64 + mt * 16 + quad * 4 + r;
        const long col = n0 + wn * 64 + nt * 16 + l15;
        store_out(C + row * N + col, acc[mt][nt][r]);
      }
}

// ------------- barrier-free paired-tile flash attention -------------
// block = (pair pt, head h, batch b): q-tiles qtA=pt, qtB=31-pt -> 33 tiles/pair.
// Waves fully independent: K/V frags loaded per-wave from global (L1/L2-hot),
// Ps round-trip in wave-private LDS, fixed-max softmax (no reductions),
// row-sum l via constant-ones B-fragment MFMA (every lane holds the sum).
__global__ __launch_bounds__(256) void attn_kernel(const __hip_bfloat16* __restrict__ qkv,
                                                   const __hip_bfloat16* __restrict__ vtg,
                                                   __hip_bfloat16* __restrict__ y) {
  __shared__ __align__(16) __hip_bfloat16 Ps[2 * 4 * 16 * 72];
  const int tid = threadIdx.x;
  const int lane = tid & 63, wv = tid >> 6;
  const int l15 = lane & 15, quad = lane >> 4;
  const int pt = blockIdx.x, h = blockIdx.y, b = blockIdx.z;
  const int qtA = pt, qtB = 31 - pt;
  const int q0A = qtA * 64, q0B = qtB * 64;
  const long bh = (long)b * 16 + h;
  const long RS = 3072;
  const float SC = 0.18033688011112042f;  // (1/8) * log2(e)

  // Q A-fragments for both tiles
  bf16x8 aqA0, aqA1, aqB0, aqB1;
  {
    const __hip_bfloat16* qpA = qkv + ((long)b * 2048 + q0A + wv * 16 + l15) * RS + h * 64 + quad * 8;
    aqA0 = *(const bf16x8*)qpA;
    aqA1 = *(const bf16x8*)(qpA + 32);
    const __hip_bfloat16* qpB = qkv + ((long)b * 2048 + q0B + wv * 16 + l15) * RS + h * 64 + quad * 8;
    aqB0 = *(const bf16x8*)qpB;
    aqB1 = *(const bf16x8*)(qpB + 32);
  }
  union { bf16x8 v; __hip_bfloat16 e[8]; } uo;
#pragma unroll
  for (int j = 0; j < 8; ++j) uo.e[j] = __float2bfloat16(1.0f);
  const bf16x8 ones = uo.v;

  floatx4 oA[4] = {}, oB[4] = {}, o4A = {}, o4B = {};
  __hip_bfloat16* PsA = Ps + wv * 1152;
  __hip_bfloat16* PsB = Ps + 4608 + wv * 1152;

  for (int kt = 0; kt <= qtB; ++kt) {
    const int kb = kt * 64;
    const bool actA = (kt <= qtA);

    // K and V^T fragments straight from global (b128, shared across A/B in regs)
    bf16x8 kf[4][2], vf[4][2];
    const __hip_bfloat16* kp0 = qkv + ((long)b * 2048 + kb + l15) * RS + 1024 + h * 64 + quad * 8;
    const __hip_bfloat16* vp0 = vtg + (bh * 64 + l15) * 2048 + kb + quad * 8;
#pragma unroll
    for (int nt = 0; nt < 4; ++nt) {
      kf[nt][0] = *(const bf16x8*)(kp0 + (long)nt * 16 * RS);
      kf[nt][1] = *(const bf16x8*)(kp0 + (long)nt * 16 * RS + 32);
      vf[nt][0] = *(const bf16x8*)(vp0 + (long)nt * 16 * 2048);
      vf[nt][1] = *(const bf16x8*)(vp0 + (long)nt * 16 * 2048 + 32);
    }

    floatx4 sB[4] = {}, sA[4] = {};
#pragma unroll
    for (int nt = 0; nt < 4; ++nt) {
      sB[nt] = MFMA16(aqB0, kf[nt][0], sB[nt]);
      sB[nt] = MFMA16(aqB1, kf[nt][1], sB[nt]);
    }
    if (actA) {
#pragma unroll
      for (int nt = 0; nt < 4; ++nt) {
        sA[nt] = MFMA16(aqA0, kf[nt][0], sA[nt]);
        sA[nt] = MFMA16(aqA1, kf[nt][1], sA[nt]);
      }
    }

    // fixed-max softmax: p = exp2(s*SC), causal-masked to 0 on diagonal tiles
    auto do_sm = [&](floatx4* s, __hip_bfloat16* PsX, bool diag, int q0X) {
#pragma unroll
      for (int nt = 0; nt < 4; ++nt)
#pragma unroll
        for (int r = 0; r < 4; ++r) {
          float p = exp2f(s[nt][r] * SC);
          if (diag && (kb + nt * 16 + l15 > q0X + wv * 16 + quad * 4 + r)) p = 0.f;
          PsX[(quad * 4 + r) * 72 + nt * 16 + l15] = __float2bfloat16(p);
        }
    };
    do_sm(sB, PsB, kt == qtB, q0B);
    if (actA) do_sm(sA, PsA, kt == qtA, q0A);

    // O += P V ; l += P 1  (in-wave LDS ordering makes write->read safe, no barrier)
    {
      const __hip_bfloat16* pp = PsB + l15 * 72 + quad * 8;
      const bf16x8 p0 = *(const bf16x8*)pp, p1 = *(const bf16x8*)(pp + 32);
#pragma unroll
      for (int nt = 0; nt < 4; ++nt) {
        oB[nt] = MFMA16(p0, vf[nt][0], oB[nt]);
        oB[nt] = MFMA16(p1, vf[nt][1], oB[nt]);
      }
      o4B = MFMA16(p0, ones, o4B);
      o4B = MFMA16(p1, ones, o4B);
    }
    if (actA) {
      const __hip_bfloat16* pp = PsA + l15 * 72 + quad * 8;
      const bf16x8 p0 = *(const bf16x8*)pp, p1 = *(const bf16x8*)(pp + 32);
#pragma unroll
      for (int nt = 0; nt < 4; ++nt) {
        oA[nt] = MFMA16(p0, vf[nt][0], oA[nt]);
        oA[nt] = MFMA16(p1, vf[nt][1], oA[nt]);
      }
      o4A = MFMA16(p0, ones, o4A);
      o4A = MFMA16(p1, ones, o4A);
    }
  }

  // epilogue: every lane of o4 col-group holds the row-sum (ones B-frag)
#pragma unroll
  for (int r = 0; r < 4; ++r) {
    const float invA = 1.0f / o4A[r];
    const float invB = 1.0f / o4B[r];
    const long tA = (long)b * 2048 + q0A + wv * 16 + quad * 4 + r;
    const long tB = (long)b * 2048 + q0B + wv * 16 + quad * 4 + r;
#pragma unroll
    for (int nt = 0; nt < 4; ++nt) {
      y[tA * 1024 + h * 64 + nt * 16 + l15] = __float2bfloat16(oA[nt][r] * invA);
      y[tB * 1024 + h * 64 + nt * 16 + l15] = __float2bfloat16(oB[nt][r] * invB);
    }
  }
}

extern "C" void kernel_launch(void* const* d_in, const int* in_sizes, int n_in,
                              void* d_out, int out_size, void* d_ws, size_t ws_size,
                              hipStream_t stream) {
  const float* x      = (const float*)d_in[0];
  const float* w_attn = (const float*)d_in[1];
  const float* w_proj = (const float*)d_in[2];
  float* out = (float*)d_out;
  char* ws = (char*)d_ws;
  __hip_bfloat16* xb   = (__hip_bfloat16*)(ws);               // then vt
  __hip_bfloat16* wat  = (__hip_bfloat16*)(ws + 8388608);     // then yb
  __hip_bfloat16* qkvb = (__hip_bfloat16*)(ws + 16777216);
  __hip_bfloat16* wpt  = (__hip_bfloat16*)(ws + 41943040);
  __hip_bfloat16* vtg  = xb;
  __hip_bfloat16* yb   = wat;

  cast_bf16_kernel<<<4096, 256, 0, stream>>>(x, xb, 4194304);
  transpose_cast_kernel<<<dim3(96, 32), dim3(32, 8), 0, stream>>>(w_attn, wat, 1024, 3072);
  transpose_cast_kernel<<<dim3(32, 32), dim3(32, 8), 0, stream>>>(w_proj, wpt, 1024, 1024);
  // qkv = x @ w_attn
  gemm_bt_kernel<__hip_bfloat16><<<dim3(24, 32), 256, 0, stream>>>(xb, wat, qkvb, 4096, 3072, 1024);
  // V^T (overwrites xb -- dead after the qkv GEMM)
  vt_kernel<<<dim3(32, 16, 2), 256, 0, stream>>>(qkvb, vtg);
  // attention (writes yb over wat -- dead after the qkv GEMM)
  attn_kernel<<<dim3(16, 16, 2), 256, 0, stream>>>(qkvb, vtg, yb);
  // out = y @ w_proj
  gemm_bt_kernel<float><<<dim3(8, 32), 256, 0, stream>>>(yb, wpt, out, 4096, 1024, 1024);
}

// Round 4
// 201.311 us; speedup vs baseline: 1.3290x; 1.3290x over previous
//
#include <hip/hip_runtime.h>
#include <hip/hip_bf16.h>

// B=2, T=2048, C=1024, H=16, Dh=64
// ws layout (bytes), total 44,040,192:
//   xb   [4096x1024] bf16 @ 0          -- reused as vt [2][16][64][2048] after qkv GEMM
//   wat  [3072x1024] bf16 @ 8388608    -- reused as yb [4096x1024] bf16 after qkv GEMM
//   qkv  [4096x3072] bf16 @ 16777216
//   wpt  [1024x1024] bf16 @ 41943040

typedef __attribute__((ext_vector_type(8))) __bf16 bf16x8;
typedef __attribute__((ext_vector_type(4))) float  floatx4;
typedef __attribute__((ext_vector_type(4))) float  fvec4;
typedef __attribute__((ext_vector_type(4))) short  short4v;

#define MFMA16(a, b, c) __builtin_amdgcn_mfma_f32_16x16x32_bf16(a, b, c, 0, 0, 0)

using as1v = const __attribute__((address_space(1))) void;
using as3v = __attribute__((address_space(3))) void;
__device__ __forceinline__ void async16(const void* g, void* l) {
  __builtin_amdgcn_global_load_lds((as1v*)g, (as3v*)l, 16, 0, 0);
}

__device__ inline void store_out(float* p, float v) { *p = v; }
__device__ inline void store_out(__hip_bfloat16* p, float v) { *p = __float2bfloat16(v); }

// ---------------- cast fp32 -> bf16 ----------------
__global__ __launch_bounds__(256) void cast_bf16_kernel(const float* __restrict__ in,
                                                        __hip_bfloat16* __restrict__ out,
                                                        int n) {
  int i = (blockIdx.x * 256 + threadIdx.x) * 4;
  if (i >= n) return;
  fvec4 v = *(const fvec4*)(in + i);
  union { short4v s; __hip_bfloat16 h[4]; } u;
#pragma unroll
  for (int j = 0; j < 4; ++j) u.h[j] = __float2bfloat16(v[j]);
  *(short4v*)((short*)out + i) = u.s;
}

// ------------- transpose + cast: in[rows][cols] f32 -> out[cols][rows] bf16 -------------
__global__ __launch_bounds__(256) void transpose_cast_kernel(const float* __restrict__ in,
                                                             __hip_bfloat16* __restrict__ out,
                                                             int rows, int cols) {
  __shared__ float tile[32][33];
  const int tx = threadIdx.x, ty = threadIdx.y;
  const int c0 = blockIdx.x * 32, r0 = blockIdx.y * 32;
#pragma unroll
  for (int i = 0; i < 32; i += 8)
    tile[ty + i][tx] = in[(long)(r0 + ty + i) * cols + c0 + tx];
  __syncthreads();
#pragma unroll
  for (int i = 0; i < 32; i += 8)
    out[(long)(c0 + ty + i) * rows + r0 + tx] = __float2bfloat16(tile[tx][ty + i]);
}

// ------------- V^T extraction: vt[b][h][d][t] = qkv[b*T+t][2048+h*64+d] -------------
__global__ __launch_bounds__(256) void vt_kernel(const __hip_bfloat16* __restrict__ qkv,
                                                 __hip_bfloat16* __restrict__ vt) {
  __shared__ __align__(16) __hip_bfloat16 tile[64 * 64];
  const int tid = threadIdx.x;
  const int tt0 = blockIdx.x * 64, h = blockIdx.y, b = blockIdx.z;
  const long bh = (long)b * 16 + h;
#pragma unroll
  for (int it = 0; it < 2; ++it) {
    const int c = it * 256 + tid;
    const int row = c >> 3, cg = c & 7;
    const int pg = cg ^ ((row >> 3) & 7);
    *(bf16x8*)(tile + row * 64 + pg * 8) =
        *(const bf16x8*)(qkv + ((long)b * 2048 + tt0 + row) * 3072 + 2048 + h * 64 + cg * 8);
  }
  __syncthreads();
#pragma unroll
  for (int it = 0; it < 2; ++it) {
    const int c = it * 256 + tid;
    const int dr = c >> 3, tg = c & 7;
    union { bf16x8 v; __hip_bfloat16 e[8]; } u;
    const int pg = (dr >> 3) ^ tg;
#pragma unroll
    for (int j = 0; j < 8; ++j)
      u.e[j] = tile[(tg * 8 + j) * 64 + pg * 8 + (dr & 7)];
    *(bf16x8*)(vt + (bh * 64 + dr) * 2048 + tt0 + tg * 8) = u.v;
  }
}

// ------------- GEMM: C[M,N] = A[M,K] * Bt[N,K]^T -------------
// 128x128 tile, BK=32, 256 threads, global_load_lds width-16 staging,
// double-buffered with ONE barrier per K-iter (loads for kt+1 in flight during
// compute of kt; the barrier's vmcnt drain covers last iter's prefetch).
template <typename OutT>
__global__ __launch_bounds__(256) void gemm_bt_kernel(const __hip_bfloat16* __restrict__ A,
                                                      const __hip_bfloat16* __restrict__ Bt,
                                                      OutT* __restrict__ C,
                                                      int M, int N, int K) {
  __shared__ __align__(16) __hip_bfloat16 As[2][128 * 32];
  __shared__ __align__(16) __hip_bfloat16 Bs[2][128 * 32];
  const int tid = threadIdx.x;
  const int lane = tid & 63, wv = tid >> 6;
  const int l15 = lane & 15, quad = lane >> 4;
  const int wm = wv >> 1, wn = wv & 1;
  const long m0 = (long)blockIdx.y * 128, n0 = (long)blockIdx.x * 128;
  floatx4 acc[4][4] = {};
  const int nk = K >> 5;

  auto issue = [&](int kt, int p) {
    const int k0 = kt << 5;
#pragma unroll
    for (int it = 0; it < 2; ++it) {
      const int c = it * 256 + tid;
      const int row = c >> 2;
      const int lcg = (c & 3) ^ ((row >> 1) & 3);
      const int ldsoff = c * 16;  // wave-uniform base + lane*16
      async16(A + (m0 + row) * K + k0 + lcg * 8, (char*)&As[p][0] + ldsoff);
      async16(Bt + (n0 + row) * K + k0 + lcg * 8, (char*)&Bs[p][0] + ldsoff);
    }
  };

  issue(0, 0);
  for (int kt = 0; kt < nk; ++kt) {
    const int p = kt & 1;
    __syncthreads();  // drains prefetch into buf p; all waves done reading buf p^1
    if (kt + 1 < nk) issue(kt + 1, p ^ 1);
    bf16x8 af[4], bfr[4];
#pragma unroll
    for (int t = 0; t < 4; ++t) {
      const int ar = wm * 64 + t * 16 + l15;
      const int br = wn * 64 + t * 16 + l15;
      af[t]  = *(const bf16x8*)(&As[p][ar * 32 + (quad ^ ((ar >> 1) & 3)) * 8]);
      bfr[t] = *(const bf16x8*)(&Bs[p][br * 32 + (quad ^ ((br >> 1) & 3)) * 8]);
    }
#pragma unroll
    for (int mt = 0; mt < 4; ++mt)
#pragma unroll
      for (int nt = 0; nt < 4; ++nt)
        acc[mt][nt] = MFMA16(af[mt], bfr[nt], acc[mt][nt]);
  }
#pragma unroll
  for (int mt = 0; mt < 4; ++mt)
#pragma unroll
    for (int nt = 0; nt < 4; ++nt)
#pragma unroll
      for (int r = 0; r < 4; ++r) {
        const long row = m0 + wm * 64 + mt * 16 + quad * 4 + r;
        const long col = n0 + wn * 64 + nt * 16 + l15;
        store_out(C + row * N + col, acc[mt][nt][r]);
      }
}

// ------------- paired-tile flash attention, LDS-staged + single-barrier dbuf -------------
// block = (pair pt, head h, batch b): q-tiles qtA=pt, qtB=31-pt -> 33 tiles/pair.
// K/Vt tiles staged via global_load_lds into unpadded 64x64 XOR-swizzled buffers
// (conflict-free staging AND fragment reads). Fixed-max softmax (no reductions),
// row-sum via constant-ones B-fragment. Ps round-trip is wave-private (no barrier).
__global__ __launch_bounds__(256) void attn_kernel(const __hip_bfloat16* __restrict__ qkv,
                                                   const __hip_bfloat16* __restrict__ vtg,
                                                   __hip_bfloat16* __restrict__ y) {
  __shared__ __align__(16) __hip_bfloat16 Ks[2][64 * 64];
  __shared__ __align__(16) __hip_bfloat16 Vt[2][64 * 64];
  __shared__ __align__(16) __hip_bfloat16 Ps[2 * 4 * 16 * 72];
  const int tid = threadIdx.x;
  const int lane = tid & 63, wv = tid >> 6;
  const int l15 = lane & 15, quad = lane >> 4;
  const int pt = blockIdx.x, h = blockIdx.y, b = blockIdx.z;
  const int qtA = pt, qtB = 31 - pt;
  const int q0A = qtA * 64, q0B = qtB * 64;
  const long bh = (long)b * 16 + h;
  const long RS = 3072;
  const float SC = 0.18033688011112042f;  // (1/8) * log2(e)

  auto issue = [&](int kt, int p) {
    const int kb = kt * 64;
#pragma unroll
    for (int it = 0; it < 2; ++it) {
      const int c = it * 256 + tid;
      const int row = c >> 3;
      const int cg = (c & 7) ^ (row & 7);
      const int ldsoff = c * 16;  // wave-uniform base + lane*16
      async16(qkv + ((long)b * 2048 + kb + row) * RS + 1024 + h * 64 + cg * 8,
              (char*)&Ks[p][0] + ldsoff);
      async16(vtg + (bh * 64 + row) * 2048 + kb + cg * 8, (char*)&Vt[p][0] + ldsoff);
    }
  };

  // Q A-fragments for both tiles
  bf16x8 aqA0, aqA1, aqB0, aqB1;
  {
    const __hip_bfloat16* qpA = qkv + ((long)b * 2048 + q0A + wv * 16 + l15) * RS + h * 64 + quad * 8;
    aqA0 = *(const bf16x8*)qpA;
    aqA1 = *(const bf16x8*)(qpA + 32);
    const __hip_bfloat16* qpB = qkv + ((long)b * 2048 + q0B + wv * 16 + l15) * RS + h * 64 + quad * 8;
    aqB0 = *(const bf16x8*)qpB;
    aqB1 = *(const bf16x8*)(qpB + 32);
  }
  union { bf16x8 v; __hip_bfloat16 e[8]; } uo;
#pragma unroll
  for (int j = 0; j < 8; ++j) uo.e[j] = __float2bfloat16(1.0f);
  const bf16x8 ones = uo.v;

  floatx4 oA[4] = {}, oB[4] = {}, o4A = {}, o4B = {};
  __hip_bfloat16* PsA = Ps + wv * 1152;
  __hip_bfloat16* PsB = Ps + 4608 + wv * 1152;

  issue(0, 0);
  for (int kt = 0; kt <= qtB; ++kt) {
    const int p = kt & 1;
    const int kb = kt * 64;
    const bool actA = (kt <= qtA);
    __syncthreads();  // drains prefetch into buf p; all waves done reading buf p^1
    if (kt < qtB) issue(kt + 1, p ^ 1);

    // K / V^T fragments from swizzled LDS (2-way max aliasing -> free)
    bf16x8 kf[4][2], vf[4][2];
#pragma unroll
    for (int nt = 0; nt < 4; ++nt) {
      const int row = nt * 16 + l15;
      const int s0 = (quad ^ (row & 7)) * 8, s1 = ((quad + 4) ^ (row & 7)) * 8;
      kf[nt][0] = *(const bf16x8*)(&Ks[p][row * 64 + s0]);
      kf[nt][1] = *(const bf16x8*)(&Ks[p][row * 64 + s1]);
      vf[nt][0] = *(const bf16x8*)(&Vt[p][row * 64 + s0]);
      vf[nt][1] = *(const bf16x8*)(&Vt[p][row * 64 + s1]);
    }

    floatx4 sB[4] = {}, sA[4] = {};
#pragma unroll
    for (int nt = 0; nt < 4; ++nt) {
      sB[nt] = MFMA16(aqB0, kf[nt][0], sB[nt]);
      sB[nt] = MFMA16(aqB1, kf[nt][1], sB[nt]);
    }
    if (actA) {
#pragma unroll
      for (int nt = 0; nt < 4; ++nt) {
        sA[nt] = MFMA16(aqA0, kf[nt][0], sA[nt]);
        sA[nt] = MFMA16(aqA1, kf[nt][1], sA[nt]);
      }
    }

    // fixed-max softmax: p = exp2(s*SC), causal-masked to 0 on diagonal tiles
    auto do_sm = [&](floatx4* s, __hip_bfloat16* PsX, bool diag, int q0X) {
#pragma unroll
      for (int nt = 0; nt < 4; ++nt)
#pragma unroll
        for (int r = 0; r < 4; ++r) {
          float pv = exp2f(s[nt][r] * SC);
          if (diag && (kb + nt * 16 + l15 > q0X + wv * 16 + quad * 4 + r)) pv = 0.f;
          PsX[(quad * 4 + r) * 72 + nt * 16 + l15] = __float2bfloat16(pv);
        }
    };
    do_sm(sB, PsB, kt == qtB, q0B);
    if (actA) do_sm(sA, PsA, kt == qtA, q0A);

    // O += P V ; l += P 1  (wave-private LDS ordering -> no barrier)
    {
      const __hip_bfloat16* pp = PsB + l15 * 72 + quad * 8;
      const bf16x8 p0 = *(const bf16x8*)pp, p1 = *(const bf16x8*)(pp + 32);
#pragma unroll
      for (int nt = 0; nt < 4; ++nt) {
        oB[nt] = MFMA16(p0, vf[nt][0], oB[nt]);
        oB[nt] = MFMA16(p1, vf[nt][1], oB[nt]);
      }
      o4B = MFMA16(p0, ones, o4B);
      o4B = MFMA16(p1, ones, o4B);
    }
    if (actA) {
      const __hip_bfloat16* pp = PsA + l15 * 72 + quad * 8;
      const bf16x8 p0 = *(const bf16x8*)pp, p1 = *(const bf16x8*)(pp + 32);
#pragma unroll
      for (int nt = 0; nt < 4; ++nt) {
        oA[nt] = MFMA16(p0, vf[nt][0], oA[nt]);
        oA[nt] = MFMA16(p1, vf[nt][1], oA[nt]);
      }
      o4A = MFMA16(p0, ones, o4A);
      o4A = MFMA16(p1, ones, o4A);
    }
  }

  // epilogue: every lane of o4 holds its row-sum (ones B-frag)
#pragma unroll
  for (int r = 0; r < 4; ++r) {
    const float invA = 1.0f / o4A[r];
    const float invB = 1.0f / o4B[r];
    const long tA = (long)b * 2048 + q0A + wv * 16 + quad * 4 + r;
    const long tB = (long)b * 2048 + q0B + wv * 16 + quad * 4 + r;
#pragma unroll
    for (int nt = 0; nt < 4; ++nt) {
      y[tA * 1024 + h * 64 + nt * 16 + l15] = __float2bfloat16(oA[nt][r] * invA);
      y[tB * 1024 + h * 64 + nt * 16 + l15] = __float2bfloat16(oB[nt][r] * invB);
    }
  }
}

extern "C" void kernel_launch(void* const* d_in, const int* in_sizes, int n_in,
                              void* d_out, int out_size, void* d_ws, size_t ws_size,
                              hipStream_t stream) {
  const float* x      = (const float*)d_in[0];
  const float* w_attn = (const float*)d_in[1];
  const float* w_proj = (const float*)d_in[2];
  float* out = (float*)d_out;
  char* ws = (char*)d_ws;
  __hip_bfloat16* xb   = (__hip_bfloat16*)(ws);               // then vt
  __hip_bfloat16* wat  = (__hip_bfloat16*)(ws + 8388608);     // then yb
  __hip_bfloat16* qkvb = (__hip_bfloat16*)(ws + 16777216);
  __hip_bfloat16* wpt  = (__hip_bfloat16*)(ws + 41943040);
  __hip_bfloat16* vtg  = xb;
  __hip_bfloat16* yb   = wat;

  cast_bf16_kernel<<<4096, 256, 0, stream>>>(x, xb, 4194304);
  transpose_cast_kernel<<<dim3(96, 32), dim3(32, 8), 0, stream>>>(w_attn, wat, 1024, 3072);
  transpose_cast_kernel<<<dim3(32, 32), dim3(32, 8), 0, stream>>>(w_proj, wpt, 1024, 1024);
  // qkv = x @ w_attn
  gemm_bt_kernel<__hip_bfloat16><<<dim3(24, 32), 256, 0, stream>>>(xb, wat, qkvb, 4096, 3072, 1024);
  // V^T (overwrites xb -- dead after the qkv GEMM)
  vt_kernel<<<dim3(32, 16, 2), 256, 0, stream>>>(qkvb, vtg);
  // attention (writes yb over wat -- dead after the qkv GEMM)
  attn_kernel<<<dim3(16, 16, 2), 256, 0, stream>>>(qkvb, vtg, yb);
  // out = y @ w_proj
  gemm_bt_kernel<float><<<dim3(8, 32), 256, 0, stream>>>(yb, wpt, out, 4096, 1024, 1024);
}